// Round 6
// baseline (232.777 us; speedup 1.0000x reference)
//
#include <hip/hip_runtime.h>

typedef __bf16 bf16x8 __attribute__((ext_vector_type(8)));
typedef __bf16 bf16x4v __attribute__((ext_vector_type(4)));
typedef float f32x4 __attribute__((ext_vector_type(4)));

typedef const void __attribute__((address_space(1)))* gas_ptr;
typedef void __attribute__((address_space(3)))* las_ptr;

__device__ __forceinline__ void gload16(const __bf16* g, __bf16* lds) {
  __builtin_amdgcn_global_load_lds((gas_ptr)g, (las_ptr)lds, 16, 0, 0);
}

#define SBAR  __builtin_amdgcn_s_barrier()
#define SCHED __builtin_amdgcn_sched_barrier(0)

// ---------------------------------------------------------------------------
__global__ __launch_bounds__(256) void cast_k(const float* __restrict__ in,
                                              __bf16* __restrict__ out, int n4) {
  int i = blockIdx.x * 256 + threadIdx.x;
  if (i >= n4) return;
  float4 v = ((const float4*)in)[i];
  bf16x4v o = { (__bf16)v.x, (__bf16)v.y, (__bf16)v.z, (__bf16)v.w };
  ((bf16x4v*)out)[i] = o;
}

__global__ __launch_bounds__(256) void cast_w_k(const float* __restrict__ w0,
                                                const float* __restrict__ w1,
                                                const float* __restrict__ w2,
                                                __bf16* __restrict__ out, int n4) {
  int z = blockIdx.y;
  const float* in = (z == 0) ? w0 : (z == 1) ? w1 : w2;
  int i = blockIdx.x * 256 + threadIdx.x;
  if (i >= n4) return;
  float4 v = ((const float4*)in)[i];
  bf16x4v o = { (__bf16)v.x, (__bf16)v.y, (__bf16)v.z, (__bf16)v.w };
  ((bf16x4v*)(out + (size_t)z * n4 * 4))[i] = o;
}

// ---------------------------------------------------------------------------
__global__ void transpose_k(const __bf16* __restrict__ V, __bf16* __restrict__ Vt,
                            int T, int C) {
  __shared__ __bf16 tile[32][33];
  int b = blockIdx.z;
  int s0 = blockIdx.x * 32, c0 = blockIdx.y * 32;
  const __bf16* Vb = V + (size_t)b * T * C;
  __bf16* Vtb = Vt + (size_t)b * C * T;
  int tx = threadIdx.x, ty = threadIdx.y;  // 32 x 8
  for (int i = ty; i < 32; i += 8) tile[i][tx] = Vb[(size_t)(s0 + i) * C + c0 + tx];
  __syncthreads();
  for (int i = ty; i < 32; i += 8) Vtb[(size_t)(c0 + i) * T + s0 + tx] = tile[tx][i];
}

// ---------------------------------------------------------------------------
__global__ __launch_bounds__(256) void softmax_causal_k(float* __restrict__ scores, int T) {
  const int row = blockIdx.x;  // b*T + t
  const int t = row & (T - 1);
  float* srow = scores + (size_t)row * T;
  __bf16* arow = (__bf16*)srow;
  __shared__ float rb[2048];
  __shared__ float redmax[4];
  __shared__ float redsum[4];
  const int tid = threadIdx.x, lane = tid & 63, wave = tid >> 6;
  const int wlim = ((t >> 8) + 1) << 8;  // PV reads only to next 256-boundary
  for (int s = tid; s < wlim; s += 256) rb[s] = (s <= t) ? srow[s] : -3.0e38f;
  __syncthreads();
  float lmax = -3.0e38f;
  for (int s = tid; s < wlim; s += 256) lmax = fmaxf(lmax, rb[s]);
#pragma unroll
  for (int off = 32; off; off >>= 1) lmax = fmaxf(lmax, __shfl_down(lmax, off));
  if (lane == 0) redmax[wave] = lmax;
  __syncthreads();
  float gmax = fmaxf(fmaxf(redmax[0], redmax[1]), fmaxf(redmax[2], redmax[3]));
  float lsum = 0.f;
  for (int s = tid; s < wlim; s += 256) {
    float e = (s <= t) ? __expf(rb[s] - gmax) : 0.f;
    rb[s] = e;
    lsum += e;
  }
#pragma unroll
  for (int off = 32; off; off >>= 1) lsum += __shfl_down(lsum, off);
  if (lane == 0) redsum[wave] = lsum;
  __syncthreads();
  float inv = 1.f / (redsum[0] + redsum[1] + redsum[2] + redsum[3]);
  for (int s = tid; s < wlim; s += 256) arow[s] = (__bf16)(rb[s] * inv);
}

// ---------------------------------------------------------------------------
// Read-ahead 4-phase NT GEMM. C[m,n] = sum_k A[m,k]*B[n,k].
// BM=256, BN=128, BK=64. 8 waves 4m x 2n; wave-row frags interleaved so
// phase q uses ONLY A row-quadrant q: row = q*64 + wm*16. acc[4][4].
// LDS 96 KiB: sA[2][256*64], sB[2][128*64], XOR-swizzled 16B chunks
// (phys_chunk = chunk ^ (row&7)) both at gload source and ds_read.
// Phase q: {stage unit | ds_read A(q+1) | sched_barrier | MFMA q (regs read
// last phase; compiler emits counted lgkm) | [vmcnt gate] | s_barrier}.
// B read once per tile at ph3 (after MFMA q3). Stage schedule during tile t:
// ph0: A-hi(t+1)->buf^1, ph1: B(t+2)->buf, ph2: A-lo(t+2)->buf.
// Gates: end-ph0 vmcnt(6) retires A-hi(t); end-ph2 vmcnt(6) retires
// B(t+1)+A-lo(t+1) (read at ph3). Stage->gate distance >= 4 phases.
// Race audit: every stage lands >=1 barrier after its region's readers
// retired (B(t) reads retire ph0 -> B staged ph1; A-lo(t) retire ph1 ->
// staged ph2; A-hi(t-1) retire ph3(t-1) -> staged ph0(t)).
// MODE 0: proj  -> bf16 out + bias ((n0>>10) selects K/Q/V slot)
// MODE 1: scores-> f32 out * scale, skip blocks with by > 2bx+1 (z = batch)
// MODE 2: PV    -> f32 out, k-tiles causal-limited (z = batch)
template <int MODE>
__global__ __launch_bounds__(512, 1) void gemm4p(
    const __bf16* __restrict__ A, const __bf16* __restrict__ B, void* __restrict__ Out,
    int lda, int ldb, int ldo, int nkt_in,
    const float* __restrict__ bias0, const float* __restrict__ bias1,
    const float* __restrict__ bias2, float scale,
    size_t sAz, size_t sBz, size_t sOz) {
  const int bx = blockIdx.x, by = blockIdx.y, z = blockIdx.z;  // x = m
  if (MODE == 1 && by > 2 * bx + 1) return;  // fully-masked tile
  const int m0 = bx * 256, n0 = by * 128;
  int nkt = nkt_in;
  if (MODE == 2) nkt = min(nkt, (bx + 1) * 4);  // causal k-limit (BK=64)

  __shared__ __align__(16) __bf16 sA[2][256 * 64];  // 64 KiB
  __shared__ __align__(16) __bf16 sB[2][128 * 64];  // 32 KiB

  const int tid = threadIdx.x, wid = tid >> 6, lane = tid & 63;
  const int lr = lane & 15, kg = lane >> 4;
  const int wm = wid & 3, wn = wid >> 2;
  const int grow = lane >> 3;                 // staging row within 8
  const int gcol = ((lane & 7) ^ grow) << 3;  // staging swizzled k-chunk

  const __bf16* Ab = A + (size_t)z * sAz + (size_t)m0 * lda;
  const __bf16* Bb = B + (size_t)z * sBz + (size_t)n0 * ldb;

  // stage unit: half h of A (128 rows, 2 gloads) into buf
  auto stA = [&](int buf, int kt, int h) {
#pragma unroll
    for (int r = 0; r < 2; ++r) {
      int br = h * 128 + r * 64 + wid * 8;  // wave-uniform base row
      gload16(Ab + (size_t)(br + grow) * lda + kt * 64 + gcol, &sA[buf][br * 64]);
    }
  };
  // stage unit: all of B (128 rows, 2 gloads)
  auto stB = [&](int buf, int kt) {
#pragma unroll
    for (int r = 0; r < 2; ++r) {
      int br = r * 64 + wid * 8;
      gload16(Bb + (size_t)(br + grow) * ldb + kt * 64 + gcol, &sB[buf][br * 64]);
    }
  };
  // A frag for phase q: row = q*64 + wm*16 + lr, 2 k-halves
  auto ldA2 = [&](bf16x8* af, int buf, int q) {
    int row = q * 64 + wm * 16 + lr;
#pragma unroll
    for (int ks = 0; ks < 2; ++ks) {
      int phys = ((ks * 4 + kg) ^ (lr & 7)) << 3;
      af[ks] = *(const bf16x8*)&sA[buf][row * 64 + phys];
    }
  };
  // all 8 B frags (4 nf x 2 ks)
  auto ldB8 = [&](bf16x8* bf, int buf) {
#pragma unroll
    for (int nf = 0; nf < 4; ++nf) {
      int row = wn * 64 + nf * 16 + lr;
#pragma unroll
      for (int ks = 0; ks < 2; ++ks) {
        int phys = ((ks * 4 + kg) ^ (lr & 7)) << 3;
        bf[nf * 2 + ks] = *(const bf16x8*)&sB[buf][row * 64 + phys];
      }
    }
  };

  f32x4 acc[4][4];
  const f32x4 zero = {0.f, 0.f, 0.f, 0.f};
#pragma unroll
  for (int m = 0; m < 4; ++m)
#pragma unroll
    for (int n = 0; n < 4; ++n) acc[m][n] = zero;

  bf16x8 bfr[8], afA[2], afB[2];

#define MMQ(q, af)                                                           \
  __builtin_amdgcn_s_setprio(1);                                             \
  _Pragma("unroll") for (int nf = 0; nf < 4; ++nf)                           \
  _Pragma("unroll") for (int ks = 0; ks < 2; ++ks)                           \
      acc[q][nf] = __builtin_amdgcn_mfma_f32_16x16x32_bf16(                  \
          af[ks], bfr[nf * 2 + ks], acc[q][nf], 0, 0, 0);                    \
  __builtin_amdgcn_s_setprio(0);

  // prologue: A(0), B(0); then B(1), A-lo(1) into buf1
  stA(0, 0, 0); stA(0, 0, 1); stB(0, 0);
  if (nkt > 1) { stB(1, 1); stA(1, 1, 0); }
  if (nkt > 1) asm volatile("s_waitcnt vmcnt(4)" ::: "memory");
  else         asm volatile("s_waitcnt vmcnt(0)" ::: "memory");
  SBAR; SCHED;
  ldB8(bfr, 0);
  ldA2(afA, 0, 0);

  for (int t = 0; t < nkt; ++t) {
    const int buf = t & 1;
    // ---- ph0: MFMA q0(afA); read q1->afB; stage A-hi(t+1)->buf^1 ----
    if (t + 1 < nkt) stA(buf ^ 1, t + 1, 1);
    ldA2(afB, buf, 1);
    SCHED;
    MMQ(0, afA)
    if (t + 1 < nkt) asm volatile("s_waitcnt vmcnt(6)" ::: "memory");
    else             asm volatile("s_waitcnt vmcnt(0)" ::: "memory");
    SBAR; SCHED;
    // ---- ph1: MFMA q1(afB); read q2->afA; stage B(t+2)->buf ----
    if (t + 2 < nkt) stB(buf, t + 2);
    ldA2(afA, buf, 2);
    SCHED;
    MMQ(1, afB)
    SBAR; SCHED;
    // ---- ph2: MFMA q2(afA); read q3->afB; stage A-lo(t+2)->buf ----
    if (t + 2 < nkt) stA(buf, t + 2, 0);
    ldA2(afB, buf, 3);
    SCHED;
    MMQ(2, afA)
    if (t + 2 < nkt)      asm volatile("s_waitcnt vmcnt(6)" ::: "memory");
    else if (t + 1 < nkt) asm volatile("s_waitcnt vmcnt(2)" ::: "memory");
    else                  asm volatile("s_waitcnt vmcnt(0)" ::: "memory");
    SBAR; SCHED;
    // ---- ph3: MFMA q3(afB); then read B(t+1)->bfr, A(q0,t+1)->afA ----
    MMQ(3, afB)
    SCHED;
    if (t + 1 < nkt) {
      ldB8(bfr, buf ^ 1);
      ldA2(afA, buf ^ 1, 0);
    }
    SBAR; SCHED;
  }

  // epilogue: D row=(lane>>4)*4+i, col=lane&15 within each 16x16 fragment
#pragma unroll
  for (int q = 0; q < 4; ++q) {
#pragma unroll
    for (int i = 0; i < 4; ++i) {
      int r = m0 + q * 64 + wm * 16 + kg * 4 + i;
#pragma unroll
      for (int nf = 0; nf < 4; ++nf) {
        int c = n0 + wn * 64 + nf * 16 + lr;
        float v = acc[q][nf][i];
        if (MODE == 0) {
          int zc = n0 >> 10, cc = c & 1023;
          const float* bias = (zc == 0) ? bias0 : (zc == 1) ? bias1 : bias2;
          ((__bf16*)Out)[(size_t)zc * sOz + (size_t)r * ldo + cc] = (__bf16)(v + bias[cc]);
        } else if (MODE == 1) {
          ((float*)Out)[(size_t)z * sOz + (size_t)r * ldo + c] = v * scale;
        } else {
          ((float*)Out)[(size_t)z * sOz + (size_t)r * ldo + c] = v;
        }
      }
    }
  }
#undef MMQ
}

// ---------------------------------------------------------------------------
extern "C" void kernel_launch(void* const* d_in, const int* in_sizes, int n_in,
                              void* d_out, int out_size, void* d_ws, size_t ws_size,
                              hipStream_t stream) {
  const float* x  = (const float*)d_in[0];
  const float* Wk = (const float*)d_in[1];
  const float* Wq = (const float*)d_in[2];
  const float* Wv = (const float*)d_in[3];
  const float* bk = (const float*)d_in[4];
  const float* bq = (const float*)d_in[5];
  const float* bv = (const float*)d_in[6];
  float* out = (float*)d_out;

  const int B = 4, T = 2048, C = 1024;
  const int M = B * T;  // 8192

  char* ws = (char*)d_ws;
  __bf16* x_bf = (__bf16*)ws;                    // 16 MB
  __bf16* w_bf = (__bf16*)(ws + 16777216);       // 6 MB  (Wk|Wq|Wv concat, 3072x1024)
  __bf16* kqv  = (__bf16*)(ws + 23068672);       // 48 MB (K|Q|V, each [M][C])
  __bf16* vt   = (__bf16*)(ws + 73400320);       // 16 MB (Vt [B][C][T])
  float*  sc   = (float*)(ws + 90177536);        // 64 MB scores; attn bf16 in-place

  cast_k<<<(M * C / 4 + 255) / 256, 256, 0, stream>>>(x, x_bf, M * C / 4);
  cast_w_k<<<dim3((C * C / 4 + 255) / 256, 3), 256, 0, stream>>>(
      Wk, Wq, Wv, w_bf, C * C / 4);

  // QKV projection as ONE GEMM: [8192,1024] x [3072,1024]^T  (32x24 = 768)
  gemm4p<0><<<dim3(M / 256, 3 * C / 128, 1), 512, 0, stream>>>(
      x_bf, w_bf, kqv, C, C, C, C / 64, bk, bq, bv, 1.f,
      (size_t)0, (size_t)0, (size_t)M * C);

  // V transpose -> Vt[b][c][s]
  transpose_k<<<dim3(T / 32, C / 32, B), dim3(32, 8), 0, stream>>>(
      kqv + 2 * (size_t)M * C, vt, T, C);

  // scores = K @ Q^T / sqrt(C), per batch; skip fully-masked tiles
  gemm4p<1><<<dim3(T / 256, T / 128, B), 512, 0, stream>>>(
      kqv, kqv + (size_t)M * C, sc, C, C, T, C / 64, nullptr, nullptr, nullptr,
      0.03125f, (size_t)T * C, (size_t)T * C, (size_t)T * T);

  // causal softmax, scores(f32) -> attn(bf16) in place
  softmax_causal_k<<<B * T, 256, 0, stream>>>(sc, T);

  // out = attn @ V  (attn bf16 rows, stride 2T; B = Vt[c][s])
  gemm4p<2><<<dim3(T / 256, C / 128, B), 512, 0, stream>>>(
      (const __bf16*)sc, vt, out, 2 * T, T, C, T / 64, nullptr, nullptr, nullptr,
      1.f, (size_t)T * 2 * T, (size_t)C * T, (size_t)T * C);
}

// Round 7
// 209.814 us; speedup vs baseline: 1.1094x; 1.1094x over previous
//
#include <hip/hip_runtime.h>

typedef __bf16 bf16x8 __attribute__((ext_vector_type(8)));
typedef __bf16 bf16x4v __attribute__((ext_vector_type(4)));
typedef float f32x4 __attribute__((ext_vector_type(4)));

typedef const void __attribute__((address_space(1)))* gas_ptr;
typedef void __attribute__((address_space(3)))* las_ptr;

__device__ __forceinline__ void gload16(const __bf16* g, __bf16* lds) {
  __builtin_amdgcn_global_load_lds((gas_ptr)g, (las_ptr)lds, 16, 0, 0);
}

#define SBAR  __builtin_amdgcn_s_barrier()
#define SCHED __builtin_amdgcn_sched_barrier(0)
#define LGKM0 asm volatile("s_waitcnt lgkmcnt(0)" ::: "memory")

// ---------------------------------------------------------------------------
__global__ __launch_bounds__(256) void cast_k(const float* __restrict__ in,
                                              __bf16* __restrict__ out, int n4) {
  int i = blockIdx.x * 256 + threadIdx.x;
  if (i >= n4) return;
  float4 v = ((const float4*)in)[i];
  bf16x4v o = { (__bf16)v.x, (__bf16)v.y, (__bf16)v.z, (__bf16)v.w };
  ((bf16x4v*)out)[i] = o;
}

__global__ __launch_bounds__(256) void cast_w_k(const float* __restrict__ w0,
                                                const float* __restrict__ w1,
                                                const float* __restrict__ w2,
                                                __bf16* __restrict__ out, int n4) {
  int z = blockIdx.y;
  const float* in = (z == 0) ? w0 : (z == 1) ? w1 : w2;
  int i = blockIdx.x * 256 + threadIdx.x;
  if (i >= n4) return;
  float4 v = ((const float4*)in)[i];
  bf16x4v o = { (__bf16)v.x, (__bf16)v.y, (__bf16)v.z, (__bf16)v.w };
  ((bf16x4v*)(out + (size_t)z * n4 * 4))[i] = o;
}

// ---------------------------------------------------------------------------
__global__ void transpose_k(const __bf16* __restrict__ V, __bf16* __restrict__ Vt,
                            int T, int C) {
  __shared__ __bf16 tile[32][33];
  int b = blockIdx.z;
  int s0 = blockIdx.x * 32, c0 = blockIdx.y * 32;
  const __bf16* Vb = V + (size_t)b * T * C;
  __bf16* Vtb = Vt + (size_t)b * C * T;
  int tx = threadIdx.x, ty = threadIdx.y;  // 32 x 8
  for (int i = ty; i < 32; i += 8) tile[i][tx] = Vb[(size_t)(s0 + i) * C + c0 + tx];
  __syncthreads();
  for (int i = ty; i < 32; i += 8) Vtb[(size_t)(c0 + i) * T + s0 + tx] = tile[tx][i];
}

// ---------------------------------------------------------------------------
__global__ __launch_bounds__(256) void softmax_causal_k(float* __restrict__ scores, int T) {
  const int row = blockIdx.x;  // b*T + t
  const int t = row & (T - 1);
  float* srow = scores + (size_t)row * T;
  __bf16* arow = (__bf16*)srow;
  __shared__ float rb[2048];
  __shared__ float redmax[4];
  __shared__ float redsum[4];
  const int tid = threadIdx.x, lane = tid & 63, wave = tid >> 6;
  const int wlim = ((t >> 8) + 1) << 8;  // PV reads at most to next 128-boundary
  for (int s = tid; s < wlim; s += 256) rb[s] = (s <= t) ? srow[s] : -3.0e38f;
  __syncthreads();
  float lmax = -3.0e38f;
  for (int s = tid; s < wlim; s += 256) lmax = fmaxf(lmax, rb[s]);
#pragma unroll
  for (int off = 32; off; off >>= 1) lmax = fmaxf(lmax, __shfl_down(lmax, off));
  if (lane == 0) redmax[wave] = lmax;
  __syncthreads();
  float gmax = fmaxf(fmaxf(redmax[0], redmax[1]), fmaxf(redmax[2], redmax[3]));
  float lsum = 0.f;
  for (int s = tid; s < wlim; s += 256) {
    float e = (s <= t) ? __expf(rb[s] - gmax) : 0.f;
    rb[s] = e;
    lsum += e;
  }
#pragma unroll
  for (int off = 32; off; off >>= 1) lsum += __shfl_down(lsum, off);
  if (lane == 0) redsum[wave] = lsum;
  __syncthreads();
  float inv = 1.f / (redsum[0] + redsum[1] + redsum[2] + redsum[3]);
  for (int s = tid; s < wlim; s += 256) arow[s] = (__bf16)(rb[s] * inv);
}

// ---------------------------------------------------------------------------
// Proj GEMM: 256x256 tile, BK=64, 8 waves (2m x 4n), acc[8][4].
// ONE barrier per phase (4/K-tile). Window W(q):
//   [lgkm0; sched; MFMA(q) using regs read in W(q-1); read frags for q+1
//    (overlap MFMA pipe); stage 1 half-unit; sched; SBAR]
// Phase 0 additionally does the serial 12-read (B(t)+A-q0(t)) + lgkm0 once.
// Stage stream: W0 A-lo(t+1)->buf^1, W1 A-hi(t+1)->buf^1, W2 B-lo(t+2)->buf,
// W3 B-hi(t+2)->buf; vmcnt(4) gate at W3 (6 units in flight -> retires all
// of tile t+1, keeps B(t+2) flying). Race audit: A(t+1) stages hit buf^1
// whose A-readers (tile t-1) retired at W(t-1.q)'s lgkm0 before the barrier
// into W(t.0); B(t+2) stages hit buf whose B(t) reads retired at W(t.0)'s
// lgkm0 before the W0->W1 barrier. Cross-wave publication of t+1 data is
// gate(vmcnt4)+barrier at W3 only; no wave reads t+1 before W(t+1.0).
// Requires nkt EVEN (static LDS buffer indices via 2-tile unroll).
__global__ __launch_bounds__(512, 1) void gemm8s(
    const __bf16* __restrict__ A, const __bf16* __restrict__ B, __bf16* __restrict__ Out,
    int lda, int ldb, int ldo, int nkt,
    const float* __restrict__ bias0, const float* __restrict__ bias1,
    const float* __restrict__ bias2, size_t sOz) {
  const int m0 = blockIdx.x * 256, n0 = blockIdx.y * 256;

  __shared__ __align__(16) __bf16 sA[2][256 * 64];  // 64 KiB
  __shared__ __align__(16) __bf16 sB[2][256 * 64];  // 64 KiB

  const int tid = threadIdx.x, wid = tid >> 6, lane = tid & 63;
  const int lr = lane & 15, kg = lane >> 4;
  const int wm = wid & 1, wn = wid >> 1;
  const int grow = lane >> 3;                 // staging row within 8
  const int gcol = ((lane & 7) ^ grow) << 3;  // staging swizzled k-chunk

  const __bf16* Ab = A + (size_t)m0 * lda;
  const __bf16* Bb = B + (size_t)n0 * ldb;

  auto stA = [&](int buf, int kt, int h) {  // half-unit: 128 rows, 2 gloads
#pragma unroll
    for (int r = 0; r < 2; ++r) {
      int br = h * 128 + r * 64 + wid * 8;
      gload16(Ab + (size_t)(br + grow) * lda + kt * 64 + gcol, &sA[buf][br * 64]);
    }
  };
  auto stB = [&](int buf, int kt, int h) {
#pragma unroll
    for (int r = 0; r < 2; ++r) {
      int br = h * 128 + r * 64 + wid * 8;
      gload16(Bb + (size_t)(br + grow) * ldb + kt * 64 + gcol, &sB[buf][br * 64]);
    }
  };

  f32x4 acc[8][4];
  const f32x4 zero = {0.f, 0.f, 0.f, 0.f};
#pragma unroll
  for (int m = 0; m < 8; ++m)
#pragma unroll
    for (int n = 0; n < 4; ++n) acc[m][n] = zero;

  bf16x8 bfr[8], afA[4], afB[4];

#define LDA2(af, buf, q)                                                      \
  _Pragma("unroll") for (int f = 0; f < 2; ++f)                               \
  _Pragma("unroll") for (int ks = 0; ks < 2; ++ks) {                          \
    int row = wm * 128 + ((q)*2 + f) * 16 + lr;                               \
    int phys = ((ks * 4 + kg) ^ (lr & 7)) << 3;                               \
    af[f * 2 + ks] = *(const bf16x8*)&sA[buf][row * 64 + phys];               \
  }
#define LDB8(buf)                                                             \
  _Pragma("unroll") for (int nf = 0; nf < 4; ++nf)                            \
  _Pragma("unroll") for (int ks = 0; ks < 2; ++ks) {                          \
    int row = wn * 64 + nf * 16 + lr;                                         \
    int phys = ((ks * 4 + kg) ^ (lr & 7)) << 3;                               \
    bfr[nf * 2 + ks] = *(const bf16x8*)&sB[buf][row * 64 + phys];             \
  }
#define MMQ(q, af)                                                            \
  __builtin_amdgcn_s_setprio(1);                                              \
  _Pragma("unroll") for (int f = 0; f < 2; ++f)                               \
  _Pragma("unroll") for (int nf = 0; nf < 4; ++nf)                            \
  _Pragma("unroll") for (int ks = 0; ks < 2; ++ks)                            \
      acc[(q)*2 + f][nf] = __builtin_amdgcn_mfma_f32_16x16x32_bf16(           \
          af[f * 2 + ks], bfr[nf * 2 + ks], acc[(q)*2 + f][nf], 0, 0, 0);     \
  __builtin_amdgcn_s_setprio(0);

  // TILE body, buf is a literal -> static LDS addressing
#define TILE(t, buf)                                                          \
  {                                                                           \
    /* W0: serial read set for q0, then MFMA q0 / read q1 / stage A-lo */     \
    LDB8(buf) LDA2(afA, buf, 0)                                               \
    LGKM0; SCHED;                                                             \
    MMQ(0, afA)                                                               \
    LDA2(afB, buf, 1)                                                         \
    if ((t) + 1 < nkt) stA(buf ^ 1, (t) + 1, 0);                              \
    SCHED; SBAR;                                                              \
    /* W1 */                                                                  \
    LGKM0; SCHED;                                                             \
    MMQ(1, afB)                                                               \
    LDA2(afA, buf, 2)                                                         \
    if ((t) + 1 < nkt) stA(buf ^ 1, (t) + 1, 1);                              \
    SCHED; SBAR;                                                              \
    /* W2 */                                                                  \
    LGKM0; SCHED;                                                             \
    MMQ(2, afA)                                                               \
    LDA2(afB, buf, 3)                                                         \
    if ((t) + 2 < nkt) stB(buf, (t) + 2, 0);                                  \
    SCHED; SBAR;                                                              \
    /* W3 */                                                                  \
    LGKM0; SCHED;                                                             \
    MMQ(3, afB)                                                               \
    if ((t) + 2 < nkt) {                                                      \
      stB(buf, (t) + 2, 1);                                                   \
      asm volatile("s_waitcnt vmcnt(4)" ::: "memory");                        \
    } else if ((t) + 1 < nkt) {                                               \
      asm volatile("s_waitcnt vmcnt(0)" ::: "memory");                        \
    }                                                                         \
    SCHED; SBAR;                                                              \
  }

  // prologue: tile0 + B(1); vmcnt(4) keeps B(1) in flight, tile0 resident
  stA(0, 0, 0); stA(0, 0, 1); stB(0, 0, 0); stB(0, 0, 1);
  if (nkt > 1) { stB(1, 1, 0); stB(1, 1, 1); }
  if (nkt > 1) asm volatile("s_waitcnt vmcnt(4)" ::: "memory");
  else         asm volatile("s_waitcnt vmcnt(0)" ::: "memory");
  SBAR;

#pragma unroll 1
  for (int t = 0; t < nkt; t += 2) {
    TILE(t, 0)
    TILE(t + 1, 1)  // nkt even by construction (K=1024, BK=64)
  }
#undef TILE
#undef MMQ
#undef LDB8
#undef LDA2

  // epilogue: D row=(lane>>4)*4+i, col=lane&15 within each 16x16 fragment
#pragma unroll
  for (int mf = 0; mf < 8; ++mf) {
#pragma unroll
    for (int i = 0; i < 4; ++i) {
      int r = m0 + wm * 128 + mf * 16 + kg * 4 + i;
#pragma unroll
      for (int nf = 0; nf < 4; ++nf) {
        int c = n0 + wn * 64 + nf * 16 + lr;
        float v = acc[mf][nf][i];
        int zc = c >> 10, cc = c & 1023;
        const float* bias = (zc == 0) ? bias0 : (zc == 1) ? bias1 : bias2;
        Out[(size_t)zc * sOz + (size_t)r * ldo + cc] = (__bf16)(v + bias[cc]);
      }
    }
  }
}

// ---------------------------------------------------------------------------
// Round-1 128x128 NT GEMM (4 waves, BK=32, 32 KiB LDS, 3+ blocks/CU —
// co-residency self-balances the causal load imbalance).
// MODE 1: scores-> f32 out * scale, skip blocks with by>bx (z = batch)
// MODE 2: PV    -> f32 out, k-tiles limited to causal range
template <int MODE>
__global__ __launch_bounds__(256) void gemm_nt(
    const __bf16* __restrict__ A, const __bf16* __restrict__ B, void* __restrict__ Out,
    int lda, int ldb, int ldo, int nkt_full, float scale,
    size_t strideA_z, size_t strideB_z, size_t strideO_z) {
  if (MODE == 1 && blockIdx.y > blockIdx.x) return;  // fully-masked tile
  const int z = blockIdx.z;
  A += (size_t)z * strideA_z;
  B += (size_t)z * strideB_z;
  const int m0 = blockIdx.x * 128;
  const int n0 = blockIdx.y * 128;
  int nkt = nkt_full;
  if (MODE == 2) nkt = min(nkt, (int)(blockIdx.x + 1) * 4);  // causal (BK=32)

  __shared__ __align__(16) __bf16 smA[2][128 * 32];
  __shared__ __align__(16) __bf16 smB[2][128 * 32];

  const int tid = threadIdx.x;
  const int lane = tid & 63;
  const int wave = tid >> 6;
  const int r_in = lane >> 2;
  const int c8 = (lane & 3) * 8;

  const __bf16* Ab = A + (size_t)m0 * lda;
  const __bf16* Bb = B + (size_t)n0 * ldb;

  auto stage = [&](int buf, int kt) {
    const int kofs = kt * 32 + c8;
#pragma unroll
    for (int rr = 0; rr < 2; ++rr) {
      int row = rr * 64 + wave * 16 + r_in;
      int chunk = (rr * 64 + wave * 16) * 32;
      gload16(Ab + (size_t)row * lda + kofs, &smA[buf][chunk]);
      gload16(Bb + (size_t)row * ldb + kofs, &smB[buf][chunk]);
    }
  };

  f32x4 acc[4][4];
  const f32x4 zero = {0.f, 0.f, 0.f, 0.f};
#pragma unroll
  for (int m = 0; m < 4; ++m)
#pragma unroll
    for (int n = 0; n < 4; ++n) acc[m][n] = zero;

  const int wr = (wave >> 1) * 64;
  const int wc = (wave & 1) * 64;
  const int lr = lane & 15;
  const int kg = lane >> 4;

  stage(0, 0);
  __syncthreads();
  int cur = 0;
  for (int kt = 0; kt < nkt; ++kt) {
    if (kt + 1 < nkt) stage(cur ^ 1, kt + 1);
    bf16x8 af[4], bfr[4];
#pragma unroll
    for (int m = 0; m < 4; ++m)
      af[m] = *(const bf16x8*)&smA[cur][(wr + m * 16 + lr) * 32 + kg * 8];
#pragma unroll
    for (int n = 0; n < 4; ++n)
      bfr[n] = *(const bf16x8*)&smB[cur][(wc + n * 16 + lr) * 32 + kg * 8];
#pragma unroll
    for (int m = 0; m < 4; ++m)
#pragma unroll
      for (int n = 0; n < 4; ++n)
        acc[m][n] = __builtin_amdgcn_mfma_f32_16x16x32_bf16(af[m], bfr[n], acc[m][n], 0, 0, 0);
    __syncthreads();
    cur ^= 1;
  }

#pragma unroll
  for (int m = 0; m < 4; ++m) {
#pragma unroll
    for (int i = 0; i < 4; ++i) {
      int r = m0 + wr + m * 16 + kg * 4 + i;
#pragma unroll
      for (int n = 0; n < 4; ++n) {
        int c = n0 + wc + n * 16 + lr;
        float v = acc[m][n][i];
        if (MODE == 1) {
          ((float*)Out)[(size_t)z * strideO_z + (size_t)r * ldo + c] = v * scale;
        } else {
          ((float*)Out)[(size_t)z * strideO_z + (size_t)r * ldo + c] = v;
        }
      }
    }
  }
}

// ---------------------------------------------------------------------------
extern "C" void kernel_launch(void* const* d_in, const int* in_sizes, int n_in,
                              void* d_out, int out_size, void* d_ws, size_t ws_size,
                              hipStream_t stream) {
  const float* x  = (const float*)d_in[0];
  const float* Wk = (const float*)d_in[1];
  const float* Wq = (const float*)d_in[2];
  const float* Wv = (const float*)d_in[3];
  const float* bk = (const float*)d_in[4];
  const float* bq = (const float*)d_in[5];
  const float* bv = (const float*)d_in[6];
  float* out = (float*)d_out;

  const int B = 4, T = 2048, C = 1024;
  const int M = B * T;  // 8192

  char* ws = (char*)d_ws;
  __bf16* x_bf = (__bf16*)ws;                    // 16 MB
  __bf16* w_bf = (__bf16*)(ws + 16777216);       // 6 MB  (Wk|Wq|Wv concat, 3072x1024)
  __bf16* kqv  = (__bf16*)(ws + 23068672);       // 48 MB (K|Q|V, each [M][C])
  __bf16* vt   = (__bf16*)(ws + 73400320);       // 16 MB (Vt [B][C][T])
  float*  sc   = (float*)(ws + 90177536);        // 64 MB scores; attn bf16 in-place

  cast_k<<<(M * C / 4 + 255) / 256, 256, 0, stream>>>(x, x_bf, M * C / 4);
  cast_w_k<<<dim3((C * C / 4 + 255) / 256, 3), 256, 0, stream>>>(
      Wk, Wq, Wv, w_bf, C * C / 4);

  // QKV projection as ONE GEMM: [8192,1024] x [3072,1024]^T
  gemm8s<<<dim3(M / 256, 3 * C / 256, 1), 512, 0, stream>>>(
      x_bf, w_bf, kqv, C, C, C, C / 64, bk, bq, bv, (size_t)M * C);

  // V transpose -> Vt[b][c][s]
  transpose_k<<<dim3(T / 32, C / 32, B), dim3(32, 8), 0, stream>>>(
      kqv + 2 * (size_t)M * C, vt, T, C);

  // scores = K @ Q^T / sqrt(C), per batch; skip fully-masked tiles
  gemm_nt<1><<<dim3(T / 128, T / 128, B), 256, 0, stream>>>(
      kqv, kqv + (size_t)M * C, sc, C, C, T, C / 32, 0.03125f,
      (size_t)T * C, (size_t)T * C, (size_t)T * T);

  // causal softmax, scores(f32) -> attn(bf16) in place
  softmax_causal_k<<<B * T, 256, 0, stream>>>(sc, T);

  // out = attn @ V  (attn bf16 rows, stride 2T; B = Vt[c][s])
  gemm_nt<2><<<dim3(T / 128, C / 128, B), 256, 0, stream>>>(
      (const __bf16*)sc, vt, out, 2 * T, T, C, T / 32, 1.f,
      (size_t)T * 2 * T, (size_t)C * T, (size_t)T * C);
}

// Round 8
// 201.089 us; speedup vs baseline: 1.1576x; 1.0434x over previous
//
#include <hip/hip_runtime.h>

typedef __bf16 bf16x8 __attribute__((ext_vector_type(8)));
typedef __bf16 bf16x4v __attribute__((ext_vector_type(4)));
typedef float f32x4 __attribute__((ext_vector_type(4)));

typedef const void __attribute__((address_space(1)))* gas_ptr;
typedef void __attribute__((address_space(3)))* las_ptr;

__device__ __forceinline__ void gload16(const __bf16* g, __bf16* lds) {
  __builtin_amdgcn_global_load_lds((gas_ptr)g, (las_ptr)lds, 16, 0, 0);
}

// ---------------------------------------------------------------------------
__global__ __launch_bounds__(256) void cast_k(const float* __restrict__ in,
                                              __bf16* __restrict__ out, int n4) {
  int i = blockIdx.x * 256 + threadIdx.x;
  if (i >= n4) return;
  float4 v = ((const float4*)in)[i];
  bf16x4v o = { (__bf16)v.x, (__bf16)v.y, (__bf16)v.z, (__bf16)v.w };
  ((bf16x4v*)out)[i] = o;
}

__global__ __launch_bounds__(256) void cast_w_k(const float* __restrict__ w0,
                                                const float* __restrict__ w1,
                                                const float* __restrict__ w2,
                                                __bf16* __restrict__ out, int n4) {
  int z = blockIdx.y;
  const float* in = (z == 0) ? w0 : (z == 1) ? w1 : w2;
  int i = blockIdx.x * 256 + threadIdx.x;
  if (i >= n4) return;
  float4 v = ((const float4*)in)[i];
  bf16x4v o = { (__bf16)v.x, (__bf16)v.y, (__bf16)v.z, (__bf16)v.w };
  ((bf16x4v*)(out + (size_t)z * n4 * 4))[i] = o;
}

// ---------------------------------------------------------------------------
__global__ void transpose_k(const __bf16* __restrict__ V, __bf16* __restrict__ Vt,
                            int T, int C) {
  __shared__ __bf16 tile[32][33];
  int b = blockIdx.z;
  int s0 = blockIdx.x * 32, c0 = blockIdx.y * 32;
  const __bf16* Vb = V + (size_t)b * T * C;
  __bf16* Vtb = Vt + (size_t)b * C * T;
  int tx = threadIdx.x, ty = threadIdx.y;  // 32 x 8
  for (int i = ty; i < 32; i += 8) tile[i][tx] = Vb[(size_t)(s0 + i) * C + c0 + tx];
  __syncthreads();
  for (int i = ty; i < 32; i += 8) Vtb[(size_t)(c0 + i) * T + s0 + tx] = tile[tx][i];
}

// ---------------------------------------------------------------------------
// per-row sum of E (bf16) over [0, wlim128) -> rinv = 1/sum  (deterministic)
__global__ __launch_bounds__(256) void rowsum_k(const __bf16* __restrict__ E,
                                                float* __restrict__ rinv, int T) {
  const int row = blockIdx.x;  // b*T + t
  const int t = row & (T - 1);
  const int wlim = ((t >> 7) + 1) << 7;  // cols PV will read
  const __bf16* er = E + (size_t)row * T;
  const int tid = threadIdx.x, lane = tid & 63, wave = tid >> 6;
  __shared__ float red[4];
  float s = 0.f;
  if (tid * 8 < wlim) {
    bf16x8 v = ((const bf16x8*)er)[tid];
#pragma unroll
    for (int j = 0; j < 8; ++j) s += (float)v[j];
  }
#pragma unroll
  for (int off = 32; off; off >>= 1) s += __shfl_down(s, off);
  if (lane == 0) red[wave] = s;
  __syncthreads();
  if (tid == 0) rinv[row] = 1.f / (red[0] + red[1] + red[2] + red[3]);
}

// ---------------------------------------------------------------------------
// Proj GEMM: 128x256 tile, BK=32, 8 waves (2m x 4n, wave 64x64), acc[4][4].
// LDS 48 KiB (2 dbuf x {A 128x32, B 256x32}) -> 2 blocks/CU; grid 768 = 3/CU
// exactly (no round waste; co-resident block fills barrier stalls).
// XOR swizzle on 16B chunks: slot(row,c) holds logical chunk c^(row&3);
// staging fetches global chunk (lane&3)^((lane>>2)&3) into linear dest;
// reads use phys = kg^(lr&3). Conflict-free both sides (each 2-row 128B line
// gets 8 distinct 16B slots).
__global__ __launch_bounds__(512, 4) void gemm_proj(
    const __bf16* __restrict__ A, const __bf16* __restrict__ B, __bf16* __restrict__ Out,
    int lda, int ldb, int ldo, int nkt,
    const float* __restrict__ bias0, const float* __restrict__ bias1,
    const float* __restrict__ bias2, size_t sOz) {
  const int m0 = blockIdx.x * 128, n0 = blockIdx.y * 256;

  __shared__ __align__(16) __bf16 sA[2][128 * 32];  // 16 KiB
  __shared__ __align__(16) __bf16 sB[2][256 * 32];  // 32 KiB

  const int tid = threadIdx.x, wid = tid >> 6, lane = tid & 63;
  const int lr = lane & 15, kg = lane >> 4;
  const int wm = wid & 1, wn = wid >> 1;
  const int grow = lane >> 2;                        // staging row within 16
  const int gcol = (((lane & 3) ^ (grow & 3))) << 3; // swizzled global chunk

  const __bf16* Ab = A + (size_t)m0 * lda;
  const __bf16* Bb = B + (size_t)n0 * ldb;

  auto stage = [&](int buf, int kt) {
    {
      int br = wid * 16;  // A: 128 rows in one round
      gload16(Ab + (size_t)(br + grow) * lda + kt * 32 + gcol, &sA[buf][br * 32]);
    }
#pragma unroll
    for (int r = 0; r < 2; ++r) {  // B: 256 rows in two rounds
      int br = r * 128 + wid * 16;
      gload16(Bb + (size_t)(br + grow) * ldb + kt * 32 + gcol, &sB[buf][br * 32]);
    }
  };

  f32x4 acc[4][4];
  const f32x4 zero = {0.f, 0.f, 0.f, 0.f};
#pragma unroll
  for (int m = 0; m < 4; ++m)
#pragma unroll
    for (int n = 0; n < 4; ++n) acc[m][n] = zero;

  stage(0, 0);
  __syncthreads();
  int cur = 0;
  for (int kt = 0; kt < nkt; ++kt) {
    if (kt + 1 < nkt) stage(cur ^ 1, kt + 1);
    bf16x8 af[4], bfr[4];
    const int phys = (kg ^ (lr & 3)) << 3;
#pragma unroll
    for (int mf = 0; mf < 4; ++mf)
      af[mf] = *(const bf16x8*)&sA[cur][(wm * 64 + mf * 16 + lr) * 32 + phys];
#pragma unroll
    for (int nf = 0; nf < 4; ++nf)
      bfr[nf] = *(const bf16x8*)&sB[cur][(wn * 64 + nf * 16 + lr) * 32 + phys];
#pragma unroll
    for (int mf = 0; mf < 4; ++mf)
#pragma unroll
      for (int nf = 0; nf < 4; ++nf)
        acc[mf][nf] = __builtin_amdgcn_mfma_f32_16x16x32_bf16(af[mf], bfr[nf], acc[mf][nf], 0, 0, 0);
    __syncthreads();
    cur ^= 1;
  }

  // epilogue: D row=(lane>>4)*4+i, col=lane&15 per 16x16 fragment
#pragma unroll
  for (int mf = 0; mf < 4; ++mf) {
#pragma unroll
    for (int i = 0; i < 4; ++i) {
      int r = m0 + wm * 64 + mf * 16 + kg * 4 + i;
#pragma unroll
      for (int nf = 0; nf < 4; ++nf) {
        int c = n0 + wn * 64 + nf * 16 + lr;
        float v = acc[mf][nf][i];
        int zc = c >> 10, cc = c & 1023;
        const float* bias = (zc == 0) ? bias0 : (zc == 1) ? bias1 : bias2;
        Out[(size_t)zc * sOz + (size_t)r * ldo + cc] = (__bf16)(v + bias[cc]);
      }
    }
  }
}

// ---------------------------------------------------------------------------
// 128x128 NT GEMM (4 waves, BK=32, 32 KiB LDS, 3+ blocks/CU), swizzled LDS.
// MODE 1: scores -> E = bf16 exp(s*scale - 8), masked c>r -> 0; skip by>bx.
// MODE 2: PV     -> f32 out * rinv[r], k-tiles causal-limited.
template <int MODE>
__global__ __launch_bounds__(256) void gemm_nt(
    const __bf16* __restrict__ A, const __bf16* __restrict__ B, void* __restrict__ Out,
    int lda, int ldb, int ldo, int nkt_full, float scale,
    const float* __restrict__ rinv_g,
    size_t strideA_z, size_t strideB_z, size_t strideO_z) {
  if (MODE == 1 && blockIdx.y > blockIdx.x) return;  // fully-masked tile
  const int z = blockIdx.z;
  A += (size_t)z * strideA_z;
  B += (size_t)z * strideB_z;
  const int m0 = blockIdx.x * 128;
  const int n0 = blockIdx.y * 128;
  int nkt = nkt_full;
  if (MODE == 2) nkt = min(nkt, (int)(blockIdx.x + 1) * 4);  // causal (BK=32)

  __shared__ __align__(16) __bf16 smA[2][128 * 32];
  __shared__ __align__(16) __bf16 smB[2][128 * 32];

  const int tid = threadIdx.x;
  const int lane = tid & 63;
  const int wave = tid >> 6;
  const int grow = lane >> 2;                         // staging row within 16
  const int gcol = (((lane & 3) ^ (grow & 3))) << 3;  // swizzled global chunk

  const __bf16* Ab = A + (size_t)m0 * lda;
  const __bf16* Bb = B + (size_t)n0 * ldb;

  auto stage = [&](int buf, int kt) {
    const int kofs = kt * 32 + gcol;
#pragma unroll
    for (int rr = 0; rr < 2; ++rr) {
      int br = rr * 64 + wave * 16;
      gload16(Ab + (size_t)(br + grow) * lda + kofs, &smA[buf][br * 32]);
      gload16(Bb + (size_t)(br + grow) * ldb + kofs, &smB[buf][br * 32]);
    }
  };

  f32x4 acc[4][4];
  const f32x4 zero = {0.f, 0.f, 0.f, 0.f};
#pragma unroll
  for (int m = 0; m < 4; ++m)
#pragma unroll
    for (int n = 0; n < 4; ++n) acc[m][n] = zero;

  const int wr = (wave >> 1) * 64;
  const int wc = (wave & 1) * 64;
  const int lr = lane & 15;
  const int kg = lane >> 4;

  stage(0, 0);
  __syncthreads();
  int cur = 0;
  for (int kt = 0; kt < nkt; ++kt) {
    if (kt + 1 < nkt) stage(cur ^ 1, kt + 1);
    bf16x8 af[4], bfr[4];
    const int phys = (kg ^ (lr & 3)) << 3;
#pragma unroll
    for (int m = 0; m < 4; ++m)
      af[m] = *(const bf16x8*)&smA[cur][(wr + m * 16 + lr) * 32 + phys];
#pragma unroll
    for (int n = 0; n < 4; ++n)
      bfr[n] = *(const bf16x8*)&smB[cur][(wc + n * 16 + lr) * 32 + phys];
#pragma unroll
    for (int m = 0; m < 4; ++m)
#pragma unroll
      for (int n = 0; n < 4; ++n)
        acc[m][n] = __builtin_amdgcn_mfma_f32_16x16x32_bf16(af[m], bfr[n], acc[m][n], 0, 0, 0);
    __syncthreads();
    cur ^= 1;
  }

#pragma unroll
  for (int m = 0; m < 4; ++m) {
#pragma unroll
    for (int i = 0; i < 4; ++i) {
      int r = m0 + wr + m * 16 + kg * 4 + i;
      float ri = (MODE == 2) ? rinv_g[z * 2048 + r] : 0.f;
#pragma unroll
      for (int n = 0; n < 4; ++n) {
        int c = n0 + wc + n * 16 + lr;
        float v = acc[m][n][i];
        if (MODE == 1) {
          float e = (c <= r) ? __expf(v * scale - 8.0f) : 0.0f;
          ((__bf16*)Out)[(size_t)z * strideO_z + (size_t)r * ldo + c] = (__bf16)e;
        } else {
          ((float*)Out)[(size_t)z * strideO_z + (size_t)r * ldo + c] = v * ri;
        }
      }
    }
  }
}

// ---------------------------------------------------------------------------
extern "C" void kernel_launch(void* const* d_in, const int* in_sizes, int n_in,
                              void* d_out, int out_size, void* d_ws, size_t ws_size,
                              hipStream_t stream) {
  const float* x  = (const float*)d_in[0];
  const float* Wk = (const float*)d_in[1];
  const float* Wq = (const float*)d_in[2];
  const float* Wv = (const float*)d_in[3];
  const float* bk = (const float*)d_in[4];
  const float* bq = (const float*)d_in[5];
  const float* bv = (const float*)d_in[6];
  float* out = (float*)d_out;

  const int B = 4, T = 2048, C = 1024;
  const int M = B * T;  // 8192

  char* ws = (char*)d_ws;
  __bf16* x_bf = (__bf16*)ws;                    // 16 MB
  __bf16* w_bf = (__bf16*)(ws + 16777216);       // 6 MB  (Wk|Wq|Wv concat)
  __bf16* kqv  = (__bf16*)(ws + 23068672);       // 48 MB (K|Q|V, each [M][C])
  __bf16* vt   = (__bf16*)(ws + 73400320);       // 16 MB (Vt [B][C][T])
  __bf16* E    = (__bf16*)(ws + 90177536);       // 32 MB (exp-scores bf16 [B][T][T])
  float*  rinv = (float*)(ws + 123731968);       // 32 KB (per-row 1/sum)

  cast_k<<<(M * C / 4 + 255) / 256, 256, 0, stream>>>(x, x_bf, M * C / 4);
  cast_w_k<<<dim3((C * C / 4 + 255) / 256, 3), 256, 0, stream>>>(
      Wk, Wq, Wv, w_bf, C * C / 4);

  // QKV projection as ONE GEMM: [8192,1024] x [3072,1024]^T  (64x12 = 768)
  gemm_proj<<<dim3(M / 128, 3 * C / 256), 512, 0, stream>>>(
      x_bf, w_bf, kqv, C, C, C, C / 32, bk, bq, bv, (size_t)M * C);

  // V transpose -> Vt[b][c][s]
  transpose_k<<<dim3(T / 32, C / 32, B), dim3(32, 8), 0, stream>>>(
      kqv + 2 * (size_t)M * C, vt, T, C);

  // E = exp(K@Q^T/32 - 8) bf16, causal-masked; skip fully-masked tiles
  gemm_nt<1><<<dim3(T / 128, T / 128, B), 256, 0, stream>>>(
      kqv, kqv + (size_t)M * C, E, C, C, T, C / 32, 0.03125f, nullptr,
      (size_t)T * C, (size_t)T * C, (size_t)T * T);

  // per-row 1/sum (deterministic)
  rowsum_k<<<B * T, 256, 0, stream>>>(E, rinv, T);

  // out = (E @ V) * rinv  (B = Vt[c][s])
  gemm_nt<2><<<dim3(T / 128, C / 128, B), 256, 0, stream>>>(
      E, vt, out, T, T, C, T / 32, 1.f, rinv,
      (size_t)T * T, (size_t)C * T, (size_t)T * C);
}

// Round 9
// 198.472 us; speedup vs baseline: 1.1728x; 1.0132x over previous
//
#include <hip/hip_runtime.h>

typedef __bf16 bf16x8 __attribute__((ext_vector_type(8)));
typedef __bf16 bf16x4v __attribute__((ext_vector_type(4)));
typedef float f32x4 __attribute__((ext_vector_type(4)));

typedef const void __attribute__((address_space(1)))* gas_ptr;
typedef void __attribute__((address_space(3)))* las_ptr;

__device__ __forceinline__ void gload16(const __bf16* g, __bf16* lds) {
  __builtin_amdgcn_global_load_lds((gas_ptr)g, (las_ptr)lds, 16, 0, 0);
}

#define SBAR  __builtin_amdgcn_s_barrier()
#define SCHED __builtin_amdgcn_sched_barrier(0)
#define LGKM0 asm volatile("s_waitcnt lgkmcnt(0)" ::: "memory")
#define VMC(n) asm volatile("s_waitcnt vmcnt(" #n ")" ::: "memory")

// ---------------------------------------------------------------------------
__global__ __launch_bounds__(256) void cast_k(const float* __restrict__ in,
                                              __bf16* __restrict__ out, int n4) {
  int i = blockIdx.x * 256 + threadIdx.x;
  if (i >= n4) return;
  float4 v = ((const float4*)in)[i];
  bf16x4v o = { (__bf16)v.x, (__bf16)v.y, (__bf16)v.z, (__bf16)v.w };
  ((bf16x4v*)out)[i] = o;
}

__global__ __launch_bounds__(256) void cast_w_k(const float* __restrict__ w0,
                                                const float* __restrict__ w1,
                                                const float* __restrict__ w2,
                                                __bf16* __restrict__ out, int n4) {
  int z = blockIdx.y;
  const float* in = (z == 0) ? w0 : (z == 1) ? w1 : w2;
  int i = blockIdx.x * 256 + threadIdx.x;
  if (i >= n4) return;
  float4 v = ((const float4*)in)[i];
  bf16x4v o = { (__bf16)v.x, (__bf16)v.y, (__bf16)v.z, (__bf16)v.w };
  ((bf16x4v*)(out + (size_t)z * n4 * 4))[i] = o;
}

// ---------------------------------------------------------------------------
__global__ void transpose_k(const __bf16* __restrict__ V, __bf16* __restrict__ Vt,
                            int T, int C) {
  __shared__ __bf16 tile[32][33];
  int b = blockIdx.z;
  int s0 = blockIdx.x * 32, c0 = blockIdx.y * 32;
  const __bf16* Vb = V + (size_t)b * T * C;
  __bf16* Vtb = Vt + (size_t)b * C * T;
  int tx = threadIdx.x, ty = threadIdx.y;  // 32 x 8
  for (int i = ty; i < 32; i += 8) tile[i][tx] = Vb[(size_t)(s0 + i) * C + c0 + tx];
  __syncthreads();
  for (int i = ty; i < 32; i += 8) Vtb[(size_t)(c0 + i) * T + s0 + tx] = tile[tx][i];
}

// ---------------------------------------------------------------------------
// per-row sum of E (bf16) over [0, wlim128) -> rinv = 1/sum  (deterministic)
__global__ __launch_bounds__(256) void rowsum_k(const __bf16* __restrict__ E,
                                                float* __restrict__ rinv, int T) {
  const int row = blockIdx.x;  // b*T + t
  const int t = row & (T - 1);
  const int wlim = ((t >> 7) + 1) << 7;  // cols PV will read
  const __bf16* er = E + (size_t)row * T;
  const int tid = threadIdx.x, lane = tid & 63, wave = tid >> 6;
  __shared__ float red[4];
  float s = 0.f;
  if (tid * 8 < wlim) {
    bf16x8 v = ((const bf16x8*)er)[tid];
#pragma unroll
    for (int j = 0; j < 8; ++j) s += (float)v[j];
  }
#pragma unroll
  for (int off = 32; off; off >>= 1) s += __shfl_down(s, off);
  if (lane == 0) red[wave] = s;
  __syncthreads();
  if (tid == 0) rinv[row] = 1.f / (red[0] + red[1] + red[2] + red[3]);
}

// ---------------------------------------------------------------------------
// Counted-vmcnt ring GEMM. C[m,n] = sum_k A[m,k]*B[n,k].  128x128, BK=32,
// 4 waves (2m x 2n, wave 64x64), acc[4][4]. LDS 48 KiB = 3-slot ring x
// {A 128x32, B 128x32}.  Per K-tile (ONE barrier):
//   { stage(t+2)->slot[(t+2)%3] (4 vmem) | ds_read tile t frags (8 b128) |
//     lgkm0; sched; 16 MFMA; vmcnt(4) [t+1 resident, t+2 flying]; s_barrier }
// Steady state NEVER drains vmcnt to 0 (T4).  3 blocks/CU co-resident.
// Race audit: slot s re-staged for tile t+2 during body t; its previous
// readers (tile t-1) retired at body t-1's lgkm0, one barrier earlier.
// Swizzle (64B rows): slot(row,c) holds chunk c ^ ((row>>1)&3); staging
// fetches global chunk (lane&3)^((lane>>3)&3) into linear dest; read
// phys = kg ^ ((lr>>1)&3).  16 lanes -> 8 bank-quads x 2 = conflict-free.
// MODE 0: proj -> bf16 + bias, XCD-remapped 1D grid (bx=r/24, by=r%24)
// MODE 1: scores -> E = bf16 exp(s*scale-8), mask c>r, skip by>bx (z=batch)
// MODE 2: PV -> f32 * rinv[r], k-tiles causal-limited (z=batch)
template <int MODE>
__global__ __launch_bounds__(256, 6) void gemm_ring(
    const __bf16* __restrict__ A, const __bf16* __restrict__ B, void* __restrict__ Out,
    int lda, int ldb, int ldo, int nkt_in, float scale,
    const float* __restrict__ bias0, const float* __restrict__ bias1,
    const float* __restrict__ bias2, const float* __restrict__ rinv_g,
    size_t sAz, size_t sBz, size_t sOz) {
  int bx, by;
  const int z = blockIdx.z;
  if (MODE == 0) {
    int r = ((blockIdx.x & 7) * 192) + (blockIdx.x >> 3);  // XCD-chunked, bijective
    bx = r / 24; by = r % 24;
  } else {
    bx = blockIdx.x; by = blockIdx.y;
    if (MODE == 1 && by > bx) return;  // fully-masked tile
  }
  const int m0 = bx * 128, n0 = by * 128;
  int nkt = nkt_in;
  if (MODE == 2) nkt = min(nkt, (bx + 1) * 4);  // causal k-limit (BK=32)

  __shared__ __align__(16) __bf16 rA[3][128 * 32];  // 24 KiB
  __shared__ __align__(16) __bf16 rB[3][128 * 32];  // 24 KiB

  const int tid = threadIdx.x, wave = tid >> 6, lane = tid & 63;
  const int lr = lane & 15, kg = lane >> 4;
  const int wr = (wave >> 1) * 64, wc = (wave & 1) * 64;
  const int grow = lane >> 2;                          // staging row within 16
  const int gcol = ((lane & 3) ^ ((lane >> 3) & 3)) << 3;  // swizzled global chunk
  const int phys = (kg ^ ((lr >> 1) & 3)) << 3;            // read slot offset

  const __bf16* Ab = A + (size_t)z * sAz + (size_t)m0 * lda;
  const __bf16* Bb = B + (size_t)z * sBz + (size_t)n0 * ldb;

  auto stage = [&](int slot, int kt) {  // 4 vmem / thread
    const int kofs = kt * 32 + gcol;
#pragma unroll
    for (int rr = 0; rr < 2; ++rr) {
      int br = rr * 64 + wave * 16;
      gload16(Ab + (size_t)(br + grow) * lda + kofs, &rA[slot][br * 32]);
      gload16(Bb + (size_t)(br + grow) * ldb + kofs, &rB[slot][br * 32]);
    }
  };

  f32x4 acc[4][4];
  const f32x4 zero = {0.f, 0.f, 0.f, 0.f};
#pragma unroll
  for (int m = 0; m < 4; ++m)
#pragma unroll
    for (int n = 0; n < 4; ++n) acc[m][n] = zero;

  // prologue: stage tiles 0,1; gate leaves stage(1) in flight
  stage(0, 0);
  if (nkt > 1) { stage(1, 1); VMC(4); }
  else         { VMC(0); }
  SBAR; SCHED;

  int cur = 0;  // slot of tile t
  for (int t = 0; t < nkt; ++t) {
    int st = cur + 2; if (st >= 3) st -= 3;  // slot of tile t+2
    if (t + 2 < nkt) stage(st, t + 2);
    bf16x8 af[4], bfr[4];
#pragma unroll
    for (int m = 0; m < 4; ++m)
      af[m] = *(const bf16x8*)&rA[cur][(wr + m * 16 + lr) * 32 + phys];
#pragma unroll
    for (int n = 0; n < 4; ++n)
      bfr[n] = *(const bf16x8*)&rB[cur][(wc + n * 16 + lr) * 32 + phys];
    LGKM0; SCHED;
    __builtin_amdgcn_s_setprio(1);
#pragma unroll
    for (int m = 0; m < 4; ++m)
#pragma unroll
      for (int n = 0; n < 4; ++n)
        acc[m][n] = __builtin_amdgcn_mfma_f32_16x16x32_bf16(af[m], bfr[n], acc[m][n], 0, 0, 0);
    __builtin_amdgcn_s_setprio(0);
    if (t + 2 < nkt)      { VMC(4); }
    else if (t + 1 < nkt) { VMC(0); }
    SBAR; SCHED;
    ++cur; if (cur >= 3) cur -= 3;
  }

  // epilogue: D row=(lane>>4)*4+i, col=lane&15 per 16x16 fragment
#pragma unroll
  for (int m = 0; m < 4; ++m) {
#pragma unroll
    for (int i = 0; i < 4; ++i) {
      int r = m0 + wr + m * 16 + kg * 4 + i;
      float ri = (MODE == 2) ? rinv_g[z * 2048 + r] : 0.f;
#pragma unroll
      for (int n = 0; n < 4; ++n) {
        int c = n0 + wc + n * 16 + lr;
        float v = acc[m][n][i];
        if (MODE == 0) {
          int zc = n0 >> 10, cc = c & 1023;
          const float* bias = (zc == 0) ? bias0 : (zc == 1) ? bias1 : bias2;
          ((__bf16*)Out)[(size_t)zc * sOz + (size_t)r * ldo + cc] = (__bf16)(v + bias[cc]);
        } else if (MODE == 1) {
          float e = (c <= r) ? __expf(v * scale - 8.0f) : 0.0f;
          ((__bf16*)Out)[(size_t)z * sOz + (size_t)r * ldo + c] = (__bf16)e;
        } else {
          ((float*)Out)[(size_t)z * sOz + (size_t)r * ldo + c] = v * ri;
        }
      }
    }
  }
}

// ---------------------------------------------------------------------------
extern "C" void kernel_launch(void* const* d_in, const int* in_sizes, int n_in,
                              void* d_out, int out_size, void* d_ws, size_t ws_size,
                              hipStream_t stream) {
  const float* x  = (const float*)d_in[0];
  const float* Wk = (const float*)d_in[1];
  const float* Wq = (const float*)d_in[2];
  const float* Wv = (const float*)d_in[3];
  const float* bk = (const float*)d_in[4];
  const float* bq = (const float*)d_in[5];
  const float* bv = (const float*)d_in[6];
  float* out = (float*)d_out;

  const int B = 4, T = 2048, C = 1024;
  const int M = B * T;  // 8192

  char* ws = (char*)d_ws;
  __bf16* x_bf = (__bf16*)ws;                    // 16 MB
  __bf16* w_bf = (__bf16*)(ws + 16777216);       // 6 MB  (Wk|Wq|Wv concat)
  __bf16* kqv  = (__bf16*)(ws + 23068672);       // 48 MB (K|Q|V, each [M][C])
  __bf16* vt   = (__bf16*)(ws + 73400320);       // 16 MB (Vt [B][C][T])
  __bf16* E    = (__bf16*)(ws + 90177536);       // 32 MB (exp-scores bf16)
  float*  rinv = (float*)(ws + 123731968);       // 32 KB (per-row 1/sum)

  cast_k<<<(M * C / 4 + 255) / 256, 256, 0, stream>>>(x, x_bf, M * C / 4);
  cast_w_k<<<dim3((C * C / 4 + 255) / 256, 3), 256, 0, stream>>>(
      Wk, Wq, Wv, w_bf, C * C / 4);

  // QKV projection as ONE GEMM: [8192,1024] x [3072,1024]^T (1536 blocks,
  // XCD-remapped in-kernel; 3 blocks/CU co-resident)
  gemm_ring<0><<<dim3(1536), 256, 0, stream>>>(
      x_bf, w_bf, kqv, C, C, C, C / 32, 1.f, bk, bq, bv, nullptr,
      (size_t)0, (size_t)0, (size_t)M * C);

  // V transpose -> Vt[b][c][s]
  transpose_k<<<dim3(T / 32, C / 32, B), dim3(32, 8), 0, stream>>>(
      kqv + 2 * (size_t)M * C, vt, T, C);

  // E = exp(K@Q^T/32 - 8) bf16, causal-masked; skip fully-masked tiles
  gemm_ring<1><<<dim3(T / 128, T / 128, B), 256, 0, stream>>>(
      kqv, kqv + (size_t)M * C, E, C, C, T, C / 32, 0.03125f,
      nullptr, nullptr, nullptr, nullptr,
      (size_t)T * C, (size_t)T * C, (size_t)T * T);

  // per-row 1/sum (deterministic)
  rowsum_k<<<B * T, 256, 0, stream>>>(E, rinv, T);

  // out = (E @ V) * rinv  (B = Vt[c][s])
  gemm_ring<2><<<dim3(T / 128, C / 128, B), 256, 0, stream>>>(
      E, vt, out, T, T, C, T / 32, 1.f, nullptr, nullptr, nullptr, rinv,
      (size_t)T * T, (size_t)C * T, (size_t)T * C);
}

// Round 10
// 190.534 us; speedup vs baseline: 1.2217x; 1.0417x over previous
//
#include <hip/hip_runtime.h>

typedef __bf16 bf16x8 __attribute__((ext_vector_type(8)));
typedef __bf16 bf16x4v __attribute__((ext_vector_type(4)));
typedef float f32x4 __attribute__((ext_vector_type(4)));

typedef const void __attribute__((address_space(1)))* gas_ptr;
typedef void __attribute__((address_space(3)))* las_ptr;

__device__ __forceinline__ void gload16(const __bf16* g, __bf16* lds) {
  __builtin_amdgcn_global_load_lds((gas_ptr)g, (las_ptr)lds, 16, 0, 0);
}

// ---------------------------------------------------------------------------
// one-shot cast: x (8M f32) then Wk|Wq|Wv (1M each) -> contiguous bf16 at out
__global__ __launch_bounds__(256) void cast_all(
    const float* __restrict__ x, const float* __restrict__ w0,
    const float* __restrict__ w1, const float* __restrict__ w2,
    __bf16* __restrict__ out) {
  int i = blockIdx.x * 256 + threadIdx.x;  // float4 index; total 2,883,584
  const float* src;
  int off;
  if (i < 2097152) {
    src = x; off = i;
  } else {
    int j = i - 2097152;
    int seg = j >> 18;            // 262144 float4 per W
    off = j & 262143;
    src = (seg == 0) ? w0 : (seg == 1) ? w1 : w2;
  }
  float4 v = ((const float4*)src)[off];
  bf16x4v o = { (__bf16)v.x, (__bf16)v.y, (__bf16)v.z, (__bf16)v.w };
  ((bf16x4v*)out)[i] = o;
}

// ---------------------------------------------------------------------------
// V[b][s][c] -> Vt[b][c][s], 64x64 tiles, bf16x8 vector loads+stores
__global__ void transpose_k(const __bf16* __restrict__ V, __bf16* __restrict__ Vt,
                            int T, int C) {
  __shared__ __bf16 tile[64][68];
  int b = blockIdx.z;
  int s0 = blockIdx.x * 64, c0 = blockIdx.y * 64;
  const __bf16* Vb = V + (size_t)b * T * C;
  __bf16* Vtb = Vt + (size_t)b * C * T;
  const int t = threadIdx.x;                  // 256
  const int sr = t >> 3, e8 = (t & 7) * 8;
#pragma unroll
  for (int it = 0; it < 2; ++it) {
    int s = it * 32 + sr;
    bf16x8 v = *(const bf16x8*)&Vb[(size_t)(s0 + s) * C + c0 + e8];
#pragma unroll
    for (int j = 0; j < 8; ++j) tile[s][e8 + j] = v[j];
  }
  __syncthreads();
#pragma unroll
  for (int it = 0; it < 2; ++it) {
    int c = it * 32 + sr;
    bf16x8 o;
#pragma unroll
    for (int j = 0; j < 8; ++j) o[j] = tile[e8 + j][c];
    *(bf16x8*)&Vtb[(size_t)(c0 + c) * T + s0 + e8] = o;
  }
}

// ---------------------------------------------------------------------------
// per-row sum of E (bf16) over [0, wlim) -> rinv = 1/sum  (deterministic)
__global__ __launch_bounds__(256) void rowsum_k(const __bf16* __restrict__ E,
                                                float* __restrict__ rinv, int T) {
  const int row = blockIdx.x;  // b*T + t
  const int t = row & (T - 1);
  const int wlim = ((t >> 7) + 1) << 7;  // cols PV will read
  const __bf16* er = E + (size_t)row * T;
  const int tid = threadIdx.x, lane = tid & 63, wave = tid >> 6;
  __shared__ float red[4];
  float s = 0.f;
  if (tid * 8 < wlim) {
    bf16x8 v = ((const bf16x8*)er)[tid];
#pragma unroll
    for (int j = 0; j < 8; ++j) s += (float)v[j];
  }
#pragma unroll
  for (int off = 32; off; off >>= 1) s += __shfl_down(s, off);
  if (lane == 0) red[wave] = s;
  __syncthreads();
  if (tid == 0) rinv[row] = 1.f / (red[0] + red[1] + red[2] + red[3]);
}

// ---------------------------------------------------------------------------
// r1-structure NT GEMM (empirically fastest): 128x128 tile, 4 waves, BK=32,
// 32 KiB double-buffered LDS (3 blocks/CU), plain __syncthreads drain,
// PLUS r9's verified conflict-free XOR swizzle:
//   staging: lane fetches global chunk (lane&3)^((lane>>3)&3) of its row
//            (gload_lds dest is linear lane*16B)
//   read:    phys = kg ^ ((lr>>1)&3)   (frag bases are 16-row aligned)
// MODE 0: proj  -> bf16 out + bias[z]  (z selects W slot / out slot)
// MODE 1: scores-> E = bf16 exp(v*scale-8), mask c>r -> 0; skip by>bx
// MODE 2: PV    -> f32 out * rinv[r], k-tiles causal-limited
template <int MODE>
__global__ __launch_bounds__(256) void gemm_nt(
    const __bf16* __restrict__ A, const __bf16* __restrict__ B, void* __restrict__ Out,
    int lda, int ldb, int ldo, int nkt_full,
    const float* __restrict__ bias0, const float* __restrict__ bias1,
    const float* __restrict__ bias2, float scale, const float* __restrict__ rinv_g,
    size_t strideA_z, size_t strideB_z, size_t strideO_z) {
  if (MODE == 1 && blockIdx.y > blockIdx.x) return;  // fully-masked tile
  const int z = blockIdx.z;
  A += (size_t)z * strideA_z;
  B += (size_t)z * strideB_z;
  const int m0 = blockIdx.x * 128;
  const int n0 = blockIdx.y * 128;
  int nkt = nkt_full;
  if (MODE == 2) nkt = min(nkt, (int)(blockIdx.x + 1) * 4);  // causal (BK=32)

  __shared__ __align__(16) __bf16 smA[2][128 * 32];
  __shared__ __align__(16) __bf16 smB[2][128 * 32];

  const int tid = threadIdx.x;
  const int lane = tid & 63;
  const int wave = tid >> 6;
  const int grow = lane >> 2;                              // staging row within 16
  const int gcol = ((lane & 3) ^ ((lane >> 3) & 3)) << 3;  // swizzled global chunk

  const __bf16* Ab = A + (size_t)m0 * lda;
  const __bf16* Bb = B + (size_t)n0 * ldb;

  auto stage = [&](int buf, int kt) {
    const int kofs = kt * 32 + gcol;
#pragma unroll
    for (int rr = 0; rr < 2; ++rr) {
      int br = rr * 64 + wave * 16;
      gload16(Ab + (size_t)(br + grow) * lda + kofs, &smA[buf][br * 32]);
      gload16(Bb + (size_t)(br + grow) * ldb + kofs, &smB[buf][br * 32]);
    }
  };

  f32x4 acc[4][4];
  const f32x4 zero = {0.f, 0.f, 0.f, 0.f};
#pragma unroll
  for (int m = 0; m < 4; ++m)
#pragma unroll
    for (int n = 0; n < 4; ++n) acc[m][n] = zero;

  const int wr = (wave >> 1) * 64;
  const int wc = (wave & 1) * 64;
  const int lr = lane & 15;
  const int kg = lane >> 4;
  const int phys = (kg ^ ((lr >> 1) & 3)) << 3;  // conflict-free read offset

  stage(0, 0);
  __syncthreads();
  int cur = 0;
  for (int kt = 0; kt < nkt; ++kt) {
    if (kt + 1 < nkt) stage(cur ^ 1, kt + 1);
    bf16x8 af[4], bfr[4];
#pragma unroll
    for (int m = 0; m < 4; ++m)
      af[m] = *(const bf16x8*)&smA[cur][(wr + m * 16 + lr) * 32 + phys];
#pragma unroll
    for (int n = 0; n < 4; ++n)
      bfr[n] = *(const bf16x8*)&smB[cur][(wc + n * 16 + lr) * 32 + phys];
#pragma unroll
    for (int m = 0; m < 4; ++m)
#pragma unroll
      for (int n = 0; n < 4; ++n)
        acc[m][n] = __builtin_amdgcn_mfma_f32_16x16x32_bf16(af[m], bfr[n], acc[m][n], 0, 0, 0);
    __syncthreads();
    cur ^= 1;
  }

  // epilogue: D row=(lane>>4)*4+i, col=lane&15 per 16x16 fragment
#pragma unroll
  for (int m = 0; m < 4; ++m) {
#pragma unroll
    for (int i = 0; i < 4; ++i) {
      int r = m0 + wr + m * 16 + kg * 4 + i;
      float ri = (MODE == 2) ? rinv_g[z * 2048 + r] : 0.f;
#pragma unroll
      for (int n = 0; n < 4; ++n) {
        int c = n0 + wc + n * 16 + lr;
        float v = acc[m][n][i];
        if (MODE == 0) {
          const float* bias = (z == 0) ? bias0 : (z == 1) ? bias1 : bias2;
          ((__bf16*)Out)[(size_t)z * strideO_z + (size_t)r * ldo + c] = (__bf16)(v + bias[c]);
        } else if (MODE == 1) {
          float e = (c <= r) ? __expf(v * scale - 8.0f) : 0.0f;
          ((__bf16*)Out)[(size_t)z * strideO_z + (size_t)r * ldo + c] = (__bf16)e;
        } else {
          ((float*)Out)[(size_t)z * strideO_z + (size_t)r * ldo + c] = v * ri;
        }
      }
    }
  }
}

// ---------------------------------------------------------------------------
extern "C" void kernel_launch(void* const* d_in, const int* in_sizes, int n_in,
                              void* d_out, int out_size, void* d_ws, size_t ws_size,
                              hipStream_t stream) {
  const float* x  = (const float*)d_in[0];
  const float* Wk = (const float*)d_in[1];
  const float* Wq = (const float*)d_in[2];
  const float* Wv = (const float*)d_in[3];
  const float* bk = (const float*)d_in[4];
  const float* bq = (const float*)d_in[5];
  const float* bv = (const float*)d_in[6];
  float* out = (float*)d_out;

  const int B = 4, T = 2048, C = 1024;
  const int M = B * T;  // 8192

  char* ws = (char*)d_ws;
  __bf16* x_bf = (__bf16*)ws;                    // 16 MB
  __bf16* w_bf = (__bf16*)(ws + 16777216);       // 6 MB (contiguous after x_bf)
  __bf16* kqv  = (__bf16*)(ws + 23068672);       // 48 MB (K|Q|V, each [M][C])
  __bf16* vt   = (__bf16*)(ws + 73400320);       // 16 MB (Vt [B][C][T])
  __bf16* E    = (__bf16*)(ws + 90177536);       // 32 MB (exp-scores bf16)
  float*  rinv = (float*)(ws + 123731968);       // 32 KB (per-row 1/sum)

  // single fused cast: x + Wk + Wq + Wv -> bf16 (contiguous dest)
  cast_all<<<11264, 256, 0, stream>>>(x, Wk, Wq, Wv, x_bf);

  // QKV projection: [8192,1024] x [1024,1024]^T, z = {K,Q,V}
  gemm_nt<0><<<dim3(M / 128, C / 128, 3), 256, 0, stream>>>(
      x_bf, w_bf, kqv, C, C, C, C / 32, bk, bq, bv, 1.f, nullptr,
      (size_t)0, (size_t)C * C, (size_t)M * C);

  // V transpose -> Vt[b][c][s]
  transpose_k<<<dim3(T / 64, C / 64, B), 256, 0, stream>>>(
      kqv + 2 * (size_t)M * C, vt, T, C);

  // E = exp(K@Q^T/32 - 8) bf16, causal-masked; skip fully-masked tiles
  gemm_nt<1><<<dim3(T / 128, T / 128, B), 256, 0, stream>>>(
      kqv, kqv + (size_t)M * C, E, C, C, T, C / 32, nullptr, nullptr, nullptr,
      0.03125f, nullptr, (size_t)T * C, (size_t)T * C, (size_t)T * T);

  // per-row 1/sum (deterministic)
  rowsum_k<<<B * T, 256, 0, stream>>>(E, rinv, T);

  // out = (E @ V) * rinv  (B = Vt[c][s])
  gemm_nt<2><<<dim3(T / 128, C / 128, B), 256, 0, stream>>>(
      E, vt, out, T, T, C, T / 32, nullptr, nullptr, nullptr, 1.f, rinv,
      (size_t)T * T, (size_t)C * T, (size_t)T * C);
}

// Round 11
// 159.621 us; speedup vs baseline: 1.4583x; 1.1937x over previous
//
#include <hip/hip_runtime.h>

typedef __bf16 bf16x8 __attribute__((ext_vector_type(8)));
typedef __bf16 bf16x4v __attribute__((ext_vector_type(4)));
typedef float f32x4 __attribute__((ext_vector_type(4)));

typedef const void __attribute__((address_space(1)))* gas_ptr;
typedef void __attribute__((address_space(3)))* las_ptr;

__device__ __forceinline__ void gload16(const __bf16* g, __bf16* lds) {
  __builtin_amdgcn_global_load_lds((gas_ptr)g, (las_ptr)lds, 16, 0, 0);
}

// ---------------------------------------------------------------------------
// one-shot cast: x (8M f32) then Wk|Wq|Wv (1M each) -> contiguous bf16 at out
__global__ __launch_bounds__(256) void cast_all(
    const float* __restrict__ x, const float* __restrict__ w0,
    const float* __restrict__ w1, const float* __restrict__ w2,
    __bf16* __restrict__ out) {
  int i = blockIdx.x * 256 + threadIdx.x;  // float4 index; total 2,883,584
  const float* src;
  int off;
  if (i < 2097152) {
    src = x; off = i;
  } else {
    int j = i - 2097152;
    int seg = j >> 18;            // 262144 float4 per W
    off = j & 262143;
    src = (seg == 0) ? w0 : (seg == 1) ? w1 : w2;
  }
  float4 v = ((const float4*)src)[off];
  bf16x4v o = { (__bf16)v.x, (__bf16)v.y, (__bf16)v.z, (__bf16)v.w };
  ((bf16x4v*)out)[i] = o;
}

// ---------------------------------------------------------------------------
// V[b][s][c] -> Vt[b][c][s], 64x64 tiles, bf16x8 vector loads+stores
__global__ void transpose_k(const __bf16* __restrict__ V, __bf16* __restrict__ Vt,
                            int T, int C) {
  __shared__ __bf16 tile[64][68];
  int b = blockIdx.z;
  int s0 = blockIdx.x * 64, c0 = blockIdx.y * 64;
  const __bf16* Vb = V + (size_t)b * T * C;
  __bf16* Vtb = Vt + (size_t)b * C * T;
  const int t = threadIdx.x;                  // 256
  const int sr = t >> 3, e8 = (t & 7) * 8;
#pragma unroll
  for (int it = 0; it < 2; ++it) {
    int s = it * 32 + sr;
    bf16x8 v = *(const bf16x8*)&Vb[(size_t)(s0 + s) * C + c0 + e8];
#pragma unroll
    for (int j = 0; j < 8; ++j) tile[s][e8 + j] = v[j];
  }
  __syncthreads();
#pragma unroll
  for (int it = 0; it < 2; ++it) {
    int c = it * 32 + sr;
    bf16x8 o;
#pragma unroll
    for (int j = 0; j < 8; ++j) o[j] = tile[e8 + j][c];
    *(bf16x8*)&Vtb[(size_t)(c0 + c) * T + s0 + e8] = o;
  }
}

// ---------------------------------------------------------------------------
// r1-structure NT GEMM (empirically fastest): 128x128 tile, 4 waves, BK=32,
// 32 KiB double-buffered LDS (3 blocks/CU), plain __syncthreads drain,
// conflict-free both-sides XOR swizzle (verified r9/r10).
// MODE 0: proj  -> bf16 out + bias[z]; grid (64m, 8n, 3z)
// MODE 1: scores-> E = bf16 exp(v*scale-8), mask c>r; per-row sums fused via
//         shfl_xor reduce + atomicAdd into rsum. Grid: flat 544 = 4z x 136
//         lower-tri tiles (sqrt decode) — no dead blocks.
// MODE 2: PV    -> f32 out / rsum[r], k-tiles causal-limited. Grid: flat 512,
//         pair (j, j+256) -> bx, 15-bx so every CU gets 68 K-tiles (LPT-balanced).
template <int MODE>
__global__ __launch_bounds__(256) void gemm_nt(
    const __bf16* __restrict__ A, const __bf16* __restrict__ B, void* __restrict__ Out,
    int lda, int ldb, int ldo, int nkt_full,
    const float* __restrict__ bias0, const float* __restrict__ bias1,
    const float* __restrict__ bias2, float scale, float* __restrict__ rsum,
    size_t strideA_z, size_t strideB_z, size_t strideO_z) {
  int bx, by, z;
  if (MODE == 0) {
    bx = blockIdx.x; by = blockIdx.y; z = blockIdx.z;
  } else if (MODE == 1) {
    int f = blockIdx.x;           // 0..543
    z = f & 3;
    int t = f >> 2;               // 0..135 lower-tri tile index
    bx = (int)((sqrtf(8.f * (float)t + 1.f) - 1.f) * 0.5f);
    while ((bx + 1) * (bx + 2) / 2 <= t) ++bx;
    while (bx * (bx + 1) / 2 > t) --bx;
    by = t - bx * (bx + 1) / 2;
  } else {
    int f = blockIdx.x;           // 0..511
    int half = f >> 8, idx = f & 255;
    int rem = idx & 31;
    by = rem >> 2; z = rem & 3;
    int bh = idx >> 5;            // 0..7
    bx = half ? bh : 15 - bh;     // pair sums to 15 -> balanced CU load
  }
  A += (size_t)z * strideA_z;
  B += (size_t)z * strideB_z;
  const int m0 = bx * 128;
  const int n0 = by * 128;
  int nkt = nkt_full;
  if (MODE == 2) nkt = min(nkt, (bx + 1) * 4);  // causal (BK=32)

  __shared__ __align__(16) __bf16 smA[2][128 * 32];
  __shared__ __align__(16) __bf16 smB[2][128 * 32];

  const int tid = threadIdx.x;
  const int lane = tid & 63;
  const int wave = tid >> 6;
  const int grow = lane >> 2;                              // staging row within 16
  const int gcol = ((lane & 3) ^ ((lane >> 3) & 3)) << 3;  // swizzled global chunk

  const __bf16* Ab = A + (size_t)m0 * lda;
  const __bf16* Bb = B + (size_t)n0 * ldb;

  auto stage = [&](int buf, int kt) {
    const int kofs = kt * 32 + gcol;
#pragma unroll
    for (int rr = 0; rr < 2; ++rr) {
      int br = rr * 64 + wave * 16;
      gload16(Ab + (size_t)(br + grow) * lda + kofs, &smA[buf][br * 32]);
      gload16(Bb + (size_t)(br + grow) * ldb + kofs, &smB[buf][br * 32]);
    }
  };

  f32x4 acc[4][4];
  const f32x4 zero = {0.f, 0.f, 0.f, 0.f};
#pragma unroll
  for (int m = 0; m < 4; ++m)
#pragma unroll
    for (int n = 0; n < 4; ++n) acc[m][n] = zero;

  const int wr = (wave >> 1) * 64;
  const int wc = (wave & 1) * 64;
  const int lr = lane & 15;
  const int kg = lane >> 4;
  const int phys = (kg ^ ((lr >> 1) & 3)) << 3;  // conflict-free read offset

  stage(0, 0);
  __syncthreads();
  int cur = 0;
  for (int kt = 0; kt < nkt; ++kt) {
    if (kt + 1 < nkt) stage(cur ^ 1, kt + 1);
    bf16x8 af[4], bfr[4];
#pragma unroll
    for (int m = 0; m < 4; ++m)
      af[m] = *(const bf16x8*)&smA[cur][(wr + m * 16 + lr) * 32 + phys];
#pragma unroll
    for (int n = 0; n < 4; ++n)
      bfr[n] = *(const bf16x8*)&smB[cur][(wc + n * 16 + lr) * 32 + phys];
#pragma unroll
    for (int m = 0; m < 4; ++m)
#pragma unroll
      for (int n = 0; n < 4; ++n)
        acc[m][n] = __builtin_amdgcn_mfma_f32_16x16x32_bf16(af[m], bfr[n], acc[m][n], 0, 0, 0);
    __syncthreads();
    cur ^= 1;
  }

  // epilogue: D row=(lane>>4)*4+i, col=lane&15 per 16x16 fragment
#pragma unroll
  for (int m = 0; m < 4; ++m) {
#pragma unroll
    for (int i = 0; i < 4; ++i) {
      int r = m0 + wr + m * 16 + kg * 4 + i;
      float ri = (MODE == 2) ? 1.0f / rsum[z * 2048 + r] : 0.f;
      float rs = 0.f;
#pragma unroll
      for (int n = 0; n < 4; ++n) {
        int c = n0 + wc + n * 16 + lr;
        float v = acc[m][n][i];
        if (MODE == 0) {
          const float* bias = (z == 0) ? bias0 : (z == 1) ? bias1 : bias2;
          ((__bf16*)Out)[(size_t)z * strideO_z + (size_t)r * ldo + c] = (__bf16)(v + bias[c]);
        } else if (MODE == 1) {
          float e = (c <= r) ? __expf(v * scale - 8.0f) : 0.0f;
          ((__bf16*)Out)[(size_t)z * strideO_z + (size_t)r * ldo + c] = (__bf16)e;
          rs += e;
        } else {
          ((float*)Out)[(size_t)z * strideO_z + (size_t)r * ldo + c] = v * ri;
        }
      }
      if (MODE == 1) {
        // reduce rs across the 16 lanes (lr) sharing this row, then one atomic
#pragma unroll
        for (int off = 1; off < 16; off <<= 1) rs += __shfl_xor(rs, off);
        if (lr == 0) atomicAdd(&rsum[z * 2048 + r], rs);
      }
    }
  }
}

// ---------------------------------------------------------------------------
extern "C" void kernel_launch(void* const* d_in, const int* in_sizes, int n_in,
                              void* d_out, int out_size, void* d_ws, size_t ws_size,
                              hipStream_t stream) {
  const float* x  = (const float*)d_in[0];
  const float* Wk = (const float*)d_in[1];
  const float* Wq = (const float*)d_in[2];
  const float* Wv = (const float*)d_in[3];
  const float* bk = (const float*)d_in[4];
  const float* bq = (const float*)d_in[5];
  const float* bv = (const float*)d_in[6];
  float* out = (float*)d_out;

  const int B = 4, T = 2048, C = 1024;
  const int M = B * T;  // 8192

  char* ws = (char*)d_ws;
  __bf16* x_bf = (__bf16*)ws;                    // 16 MB
  __bf16* w_bf = (__bf16*)(ws + 16777216);       // 6 MB (contiguous after x_bf)
  __bf16* kqv  = (__bf16*)(ws + 23068672);       // 48 MB (K|Q|V, each [M][C])
  __bf16* vt   = (__bf16*)(ws + 73400320);       // 16 MB (Vt [B][C][T])
  __bf16* E    = (__bf16*)(ws + 90177536);       // 32 MB (exp-scores bf16)
  float*  rsum = (float*)(ws + 123731968);       // 32 KB (per-row sum, atomics)

  // single fused cast: x + Wk + Wq + Wv -> bf16 (contiguous dest)
  cast_all<<<11264, 256, 0, stream>>>(x, Wk, Wq, Wv, x_bf);

  // zero the row-sum accumulator (re-zeroed every launch; graph-capture safe)
  hipMemsetAsync(rsum, 0, (size_t)M * sizeof(float), stream);

  // QKV projection: [8192,1024] x [1024,1024]^T, z = {K,Q,V}
  gemm_nt<0><<<dim3(M / 128, C / 128, 3), 256, 0, stream>>>(
      x_bf, w_bf, kqv, C, C, C, C / 32, bk, bq, bv, 1.f, nullptr,
      (size_t)0, (size_t)C * C, (size_t)M * C);

  // V transpose -> Vt[b][c][s]
  transpose_k<<<dim3(T / 64, C / 64, B), 256, 0, stream>>>(
      kqv + 2 * (size_t)M * C, vt, T, C);

  // E = exp(K@Q^T/32 - 8) bf16, causal-masked, + fused row sums (atomics).
  // Flat 544-block grid: 4 batches x 136 lower-tri tiles, no dead blocks.
  gemm_nt<1><<<dim3(544), 256, 0, stream>>>(
      kqv, kqv + (size_t)M * C, E, C, C, T, C / 32, nullptr, nullptr, nullptr,
      0.03125f, rsum, (size_t)T * C, (size_t)T * C, (size_t)T * T);

  // out = (E @ V) / rsum[r]  (B = Vt[c][s]); flat 512-block LPT-balanced grid
  gemm_nt<2><<<dim3(512), 256, 0, stream>>>(
      E, vt, out, T, T, C, T / 32, nullptr, nullptr, nullptr, 1.f, rsum,
      (size_t)T * T, (size_t)C * T, (size_t)T * C);
}